// Round 1
// baseline (69.703 us; speedup 1.0000x reference)
//
#include <hip/hip_runtime.h>
#include <math.h>

#define NV 8
#define NBINS 128
#define GRID_A 64

// ws layout (floats):
// [0, 512)      pmin[GRID_A][8]
// [512, 1024)   pmax[GRID_A][8]
// [1024, 1032)  fmin[8]
// [1032, 1040)  fmax[8]

__global__ __launch_bounds__(256) void k_colminmax(const float* __restrict__ feats,
                                                   float* __restrict__ ws, int n) {
    const int tid = threadIdx.x;
    const int gt = blockIdx.x * blockDim.x + tid;
    const int nth = blockDim.x * gridDim.x;
    float lmin[NV], lmax[NV];
#pragma unroll
    for (int c = 0; c < NV; ++c) { lmin[c] = __builtin_inff(); lmax[c] = -__builtin_inff(); }
    const int n4 = n >> 2;
    const float4* f4 = (const float4*)feats;
    // stride (nth) is even in quads, so each thread's quad parity is fixed:
    // quad q covers columns (4q)&7 .. +3, i.e. cols 0-3 or 4-7.
    if (((gt << 2) & 7) == 0) {
        for (int q = gt; q < n4; q += nth) {
            float4 v = f4[q];
            lmin[0] = fminf(lmin[0], v.x); lmax[0] = fmaxf(lmax[0], v.x);
            lmin[1] = fminf(lmin[1], v.y); lmax[1] = fmaxf(lmax[1], v.y);
            lmin[2] = fminf(lmin[2], v.z); lmax[2] = fmaxf(lmax[2], v.z);
            lmin[3] = fminf(lmin[3], v.w); lmax[3] = fmaxf(lmax[3], v.w);
        }
    } else {
        for (int q = gt; q < n4; q += nth) {
            float4 v = f4[q];
            lmin[4] = fminf(lmin[4], v.x); lmax[4] = fmaxf(lmax[4], v.x);
            lmin[5] = fminf(lmin[5], v.y); lmax[5] = fmaxf(lmax[5], v.y);
            lmin[6] = fminf(lmin[6], v.z); lmax[6] = fmaxf(lmax[6], v.z);
            lmin[7] = fminf(lmin[7], v.w); lmax[7] = fmaxf(lmax[7], v.w);
        }
    }
    // generic tail (n % 4 != 0) — static-index via unrolled predicate
    for (int i = (n4 << 2) + gt; i < n; i += nth) {
        float v = feats[i];
        int c = i & 7;
#pragma unroll
        for (int cc = 0; cc < NV; ++cc)
            if (cc == c) { lmin[cc] = fminf(lmin[cc], v); lmax[cc] = fmaxf(lmax[cc], v); }
    }
    // 64-lane wave reduce per column
#pragma unroll
    for (int c = 0; c < NV; ++c) {
        float mn = lmin[c], mx = lmax[c];
#pragma unroll
        for (int m = 32; m >= 1; m >>= 1) {
            mn = fminf(mn, __shfl_xor(mn, m));
            mx = fmaxf(mx, __shfl_xor(mx, m));
        }
        lmin[c] = mn; lmax[c] = mx;
    }
    __shared__ float smin[4][NV], smax[4][NV];
    const int wave = tid >> 6, lane = tid & 63;
    if (lane == 0) {
#pragma unroll
        for (int c = 0; c < NV; ++c) { smin[wave][c] = lmin[c]; smax[wave][c] = lmax[c]; }
    }
    __syncthreads();
    if (tid < NV) {
        float mn = fminf(fminf(smin[0][tid], smin[1][tid]), fminf(smin[2][tid], smin[3][tid]));
        float mx = fmaxf(fmaxf(smax[0][tid], smax[1][tid]), fmaxf(smax[2][tid], smax[3][tid]));
        ws[blockIdx.x * NV + tid] = mn;
        ws[GRID_A * NV + blockIdx.x * NV + tid] = mx;
    }
}

__global__ __launch_bounds__(64) void k_combine(float* __restrict__ ws) {
    const int t = threadIdx.x;  // one lane per partial block, 64 lanes = GRID_A
    float mn[NV], mx[NV];
#pragma unroll
    for (int c = 0; c < NV; ++c) {
        mn[c] = ws[t * NV + c];
        mx[c] = ws[GRID_A * NV + t * NV + c];
    }
#pragma unroll
    for (int c = 0; c < NV; ++c) {
#pragma unroll
        for (int m = 32; m >= 1; m >>= 1) {
            mn[c] = fminf(mn[c], __shfl_xor(mn[c], m));
            mx[c] = fmaxf(mx[c], __shfl_xor(mx[c], m));
        }
    }
    if (t == 0) {
#pragma unroll
        for (int c = 0; c < NV; ++c) {
            ws[2 * GRID_A * NV + c] = mn[c];
            ws[2 * GRID_A * NV + NV + c] = mx[c];
        }
    }
}

// Exact replication of the reference bin rule:
//   bins = argmax over b of (diff<=0 kept) where diff = rint((lin_b - feat)*1e6)
//   == largest b with rintf((lin_b - feat)*1e6) <= 0   (diffs strictly increasing in b)
// lin built with separate f32 mul/add (NO fma) to match numpy.
__global__ __launch_bounds__(256) void k_quantize(const float* __restrict__ feats,
                                                  const float* __restrict__ ws,
                                                  float* __restrict__ out, int n) {
    __shared__ float slin[NV * 129];  // +1 pad: bank = (129v+b)%32 = (v+b)%32, conflict-free
    __shared__ float sfmin[NV], sstep[NV];
    const int tid = threadIdx.x;
    const float* fm = ws + 2 * GRID_A * NV;
    for (int e = tid; e < NV * NBINS; e += blockDim.x) {
        int v = e >> 7;
        int b = e & 127;
        float fmin = fm[v];
        float range = __fsub_rn(fm[NV + v], fmin);       // (fmax - fmin), f32
        float tb = __fdiv_rn((float)b, 127.0f);          // t[b] = b/127, f32
        slin[v * 129 + b] = __fadd_rn(fmin, __fmul_rn(range, tb));  // mul then add, no FMA
    }
    __syncthreads();
    if (tid < NV) {
        sfmin[tid] = slin[tid * 129 + 0];
        sstep[tid] = __fsub_rn(slin[tid * 129 + 1], slin[tid * 129 + 0]);
    }
    __syncthreads();
    const int i = blockIdx.x * blockDim.x + tid;
    if (i >= n) return;
    const int v = i & 7;
    const float feat = feats[i];
    const float fmin = sfmin[v];
    const float step = sstep[v];
    const float* lv = &slin[v * 129];
    // candidate, then exact monotone fix-up (cond evals ~2-3 typical)
    int b = (int)floorf((feat - fmin) / step);
    b = b < 0 ? 0 : (b > 127 ? 127 : b);
    while (b < NBINS - 1 &&
           rintf(__fmul_rn(__fsub_rn(lv[b + 1], feat), 1.0e6f)) <= 0.0f) ++b;
    while (b > 0 &&
           rintf(__fmul_rn(__fsub_rn(lv[b], feat), 1.0e6f)) > 0.0f) --b;
    const float val = lv[b];
    const float reg = __fdiv_rn(fmaxf(__fsub_rn(feat, val), 0.0f), step);
    out[i] = (float)b;       // bins output, written as float
    out[n + i] = reg;        // regs output
}

extern "C" void kernel_launch(void* const* d_in, const int* in_sizes, int n_in,
                              void* d_out, int out_size, void* d_ws, size_t ws_size,
                              hipStream_t stream) {
    const float* feats = (const float*)d_in[0];
    float* ws = (float*)d_ws;
    float* out = (float*)d_out;
    const int n = in_sizes[0];  // 100000 * 8 flat
    k_colminmax<<<GRID_A, 256, 0, stream>>>(feats, ws, n);
    k_combine<<<1, 64, 0, stream>>>(ws);
    k_quantize<<<(n + 255) / 256, 256, 0, stream>>>(feats, ws, out, n);
}